// Round 3
// baseline (139.537 us; speedup 1.0000x reference)
//
#include <hip/hip_runtime.h>
#include <hip/hip_bf16.h>
#include <stdint.h>

// Problem constants
#define BB 8
#define NN 4096
#define NE 8190
#define VV 256
#define HH 128
#define MAXD 32     // raw (with-duplicate) degree capacity; Poisson(2) max ~14
#define SLICES 32   // pool accumulation slices per batch
#define RPB 8       // rows per block in fused kernel

// ---------------------------------------------------------------------------
// K1: raw scatter into compact out/in lists (dupes kept, deduped later).
//     deg[2*row] = raw outdeg, deg[2*row+1] = raw indeg.
__global__ void k_scatter(const int* __restrict__ edges,
                          int* __restrict__ deg,
                          unsigned short* __restrict__ outl,
                          unsigned short* __restrict__ inl) {
    int idx = blockIdx.x * blockDim.x + threadIdx.x;
    if (idx >= BB * NE) return;
    int b = idx / NE;
    int src = edges[idx * 2 + 0];
    int dst = edges[idx * 2 + 1];
    int row = b * NN + src;
    int col = b * NN + dst;
    int po = atomicAdd(&deg[2 * row + 0], 1);
    if (po < MAXD) outl[(size_t)row * MAXD + po] = (unsigned short)dst;
    int pi = atomicAdd(&deg[2 * col + 1], 1);
    if (pi < MAXD) inl[(size_t)col * MAXD + pi] = (unsigned short)src;
}

// ---------------------------------------------------------------------------
// K2 (specialized blocks):
//  blocks [0,128): meta[row] = {dis = rsqrt(uniq_outdeg+1), tid} (8 B packed)
//  blocks [128,384): embW1[v,o] = sum_k emb[v,k]*w1[o,k], 2 rows per block
__global__ void k_meta_embw1(const int* __restrict__ type_ids,
                             const int* __restrict__ deg,
                             const unsigned short* __restrict__ outl,
                             const float* __restrict__ emb,
                             const float* __restrict__ w1,
                             float2* __restrict__ meta,
                             float* __restrict__ embw1) {
    int blk = blockIdx.x, t = threadIdx.x;
    if (blk < 128) {
        int row = blk * 256 + t;
        int raw = min(deg[2 * row], MAXD);
        unsigned short c[MAXD];
        for (int k = 0; k < raw; k++) c[k] = outl[(size_t)row * MAXD + k];
        int uniq = 0;
        for (int k = 0; k < raw; k++) {
            bool dup = false;
            for (int j = 0; j < k; j++) dup |= (c[j] == c[k]);
            uniq += dup ? 0 : 1;
        }
        float2 m;
        m.x = rsqrtf((float)(uniq + 1));
        m.y = __int_as_float(type_ids[row]);
        meta[row] = m;
    } else {
        __shared__ float er[256];
        int v = (blk - 128) * 2 + (t >> 7);
        int o = t & 127;
        er[t] = emb[v * HH + o];
        __syncthreads();
        const float* erow = &er[(t >> 7) * HH];
        float acc = 0.f;
#pragma unroll 8
        for (int k = 0; k < HH; k++) acc += erow[k] * w1[o * HH + k];
        embw1[v * HH + o] = acc;
    }
}

// ---------------------------------------------------------------------------
// K3: fused SpMM + bias + relu + column-weighted mean-pool accumulation.
//     Per row i (dup entries masked to zero weight):
//       acc_t  = dis_i*embW1[tid_i][t] + sum_j dis_j*embW1[tid_j][t]
//       h_t    = relu(dis_i*acc_t + b1_t)
//       c_i    = dis_i*(s_i + dis_i),  s_i = sum_u dis_u over unique in-nbrs
//       psum_t += c_i * h_t
__global__ void k_fused(const float2* __restrict__ meta,
                        const float* __restrict__ embw1,
                        const int* __restrict__ deg,
                        const unsigned short* __restrict__ outl,
                        const unsigned short* __restrict__ inl,
                        const float* __restrict__ b1,
                        float* __restrict__ p) {
    __shared__ unsigned short colso[MAXD], colsi[MAXD];
    __shared__ float djs[MAXD];
    __shared__ int   tjs[MAXD];
    __shared__ float s_sh;
    int t = threadIdx.x;
    int blk = blockIdx.x;
    int base = blk * RPB;
    int b = base >> 12;
    float b1t = b1[t];
    float psum = 0.f;

    for (int r = 0; r < RPB; r++) {
        int row = base + r;
        int rawo = min(deg[2 * row + 0], MAXD);
        int rawi = min(deg[2 * row + 1], MAXD);
        if (t < rawo) colso[t] = outl[(size_t)row * MAXD + t];
        if (t < rawi) colsi[t] = inl[(size_t)row * MAXD + t];
        __syncthreads();
        // out-neighbors: first-occurrence mask, meta load (single 8B chain)
        if (t < rawo) {
            unsigned short cc = colso[t];
            bool dup = false;
            for (int j = 0; j < t; j++) dup |= (colso[j] == cc);
            float2 m = meta[b * NN + cc];
            djs[t] = dup ? 0.f : m.x;
            tjs[t] = __float_as_int(m.y);
        }
        float sloc = 0.f;
        if (t < rawi) {
            unsigned short cc = colsi[t];
            bool dup = false;
            for (int j = 0; j < t; j++) dup |= (colsi[j] == cc);
            sloc = dup ? 0.f : meta[b * NN + cc].x;
        }
        // entries live in lanes 0..31 -> 32-lane shuffle reduce on wave 0
        if (t < 64) {
#pragma unroll
            for (int off = 16; off >= 1; off >>= 1)
                sloc += __shfl_down(sloc, off, 32);
            if (t == 0) s_sh = sloc;
        }
        __syncthreads();
        float2 mi = meta[row];
        float dis_i = mi.x;
        float acc = dis_i * embw1[__float_as_int(mi.y) * HH + t]; // eye term
        for (int q = 0; q < rawo; q++)
            acc += djs[q] * embw1[tjs[q] * HH + t];
        float h = fmaxf(dis_i * acc + b1t, 0.f);
        psum += dis_i * (s_sh + dis_i) * h;
        __syncthreads();
    }
    int slice = blk & (SLICES - 1);
    atomicAdd(&p[((size_t)b * SLICES + slice) * HH + t], psum);
}

// ---------------------------------------------------------------------------
// K4: sum slices, zbar = (pool/N) @ w2^T + b2, L2-normalize.
__global__ void k_final(const float* __restrict__ p,
                        const float* __restrict__ w2,
                        const float* __restrict__ b2,
                        float* __restrict__ out) {
    __shared__ float pl[HH];
    __shared__ float red[HH];
    int b = blockIdx.x, o = threadIdx.x;
    float accp = 0.f;
#pragma unroll 8
    for (int sct = 0; sct < SLICES; sct++)
        accp += p[((size_t)b * SLICES + sct) * HH + o];
    pl[o] = accp * (1.0f / (float)NN);
    __syncthreads();
    float acc = b2[o];
#pragma unroll 8
    for (int k = 0; k < HH; k++) acc += pl[k] * w2[o * HH + k];
    red[o] = acc * acc;
    __syncthreads();
    for (int stride = 64; stride > 0; stride >>= 1) {
        if (o < stride) red[o] += red[o + stride];
        __syncthreads();
    }
    float denom = fmaxf(sqrtf(red[0]), 1e-12f);
    out[b * HH + o] = acc / denom;
}

// ---------------------------------------------------------------------------
extern "C" void kernel_launch(void* const* d_in, const int* in_sizes, int n_in,
                              void* d_out, int out_size, void* d_ws, size_t ws_size,
                              hipStream_t stream) {
    const int*   type_ids = (const int*)d_in[0];   // [B,N]
    const int*   edges    = (const int*)d_in[1];   // [B,E,2]
    const float* emb      = (const float*)d_in[2]; // [V,H]
    const float* w1       = (const float*)d_in[3]; // [H,H]
    const float* b1       = (const float*)d_in[4]; // [H]
    const float* w2       = (const float*)d_in[5]; // [OUT,H]
    const float* b2       = (const float*)d_in[6]; // [OUT]
    float* out = (float*)d_out;                    // [B,OUT] f32

    // Workspace: [zeroed: deg 256KB | p 128KB] [outl 2MB | inl 2MB | meta 256KB | embw1 128KB]
    char* ws = (char*)d_ws;
    int* deg = (int*)ws;
    size_t off = (size_t)BB * NN * 2 * 4;                       // 256 KB
    float* p = (float*)(ws + off); off += (size_t)BB * SLICES * HH * 4;
    size_t zero_bytes = off;
    unsigned short* outl = (unsigned short*)(ws + off); off += (size_t)BB * NN * MAXD * 2;
    unsigned short* inl  = (unsigned short*)(ws + off); off += (size_t)BB * NN * MAXD * 2;
    float2* meta = (float2*)(ws + off); off += (size_t)BB * NN * 8;
    float* embw1 = (float*)(ws + off);

    hipMemsetAsync(ws, 0, zero_bytes, stream);

    k_scatter<<<(BB * NE + 255) / 256, 256, 0, stream>>>(edges, deg, outl, inl);
    k_meta_embw1<<<384, 256, 0, stream>>>(type_ids, deg, outl, emb, w1, meta, embw1);
    k_fused<<<BB * NN / RPB, HH, 0, stream>>>(meta, embw1, deg, outl, inl, b1, p);
    k_final<<<BB, HH, 0, stream>>>(p, w2, b2, out);
}